// Round 1
// baseline (848.791 us; speedup 1.0000x reference)
//
#include <hip/hip_runtime.h>

// Problem: out[b,i,k,d] = tar[b,i,k] * sum_j (A[b,i,j]*Am[b,i,j]) * (B[b,j,k,d]*Bm[b,j,k])
// B_SZ=16, N=256, D=64.
// Strategy: per-(b,k) GEMM M=256,K=256,N=64 with bf16 MFMA 16x16x32, HBM-bound.

typedef __attribute__((ext_vector_type(8))) short short8;
typedef __attribute__((ext_vector_type(4))) float f32x4;

static __device__ __forceinline__ unsigned short f2bf(float f){
  union { float f; unsigned u; } v; v.f = f;
  unsigned r = v.u + 0x7FFFu + ((v.u >> 16) & 1u);   // RNE
  return (unsigned short)(r >> 16);
}

// Mask storage dtype is detected at runtime: 0=u8,1=i32,2=i64,3=f32,4=f64
static __device__ __forceinline__ unsigned char mask_elem(const void* p, long i, int flag){
  switch(flag){
    case 0:  return ((const unsigned char*)p)[i] ? 1 : 0;
    case 1:  return ((const int*)p)[i] ? 1 : 0;
    case 2:  return ((const long long*)p)[i] ? 1 : 0;
    case 3:  return ((const float*)p)[i] != 0.f ? 1 : 0;
    default: return ((const double*)p)[i] != 0.0 ? 1 : 0;
  }
}

// A_mask[0,0,0] and [0,0,1] are guaranteed True (lengths >= N/2), so the byte
// pattern at the start of the buffer identifies the element size/format.
__global__ void detect_k(const unsigned char* m, int* flag){
  unsigned char b0=m[0], b1=m[1], b3=m[3], b4=m[4];
  int f;
  if(b0==1 && b1==1)      f = 0;              // bool / u8: 1,1,...
  else if(b0==1)          f = (b4==1)?1:2;    // i32: 1,0,0,0,1  i64: 1,0,0,0,0
  else                    f = (b3==0x3f)?3:4; // f32 1.0f: 00 00 80 3f ; f64: byte3==0
  *flag = f;
}

// Pre-mask A and convert to bf16 (16*256*256 elements)
__global__ void prep_A(const float* __restrict__ A, const void* __restrict__ Am,
                       unsigned short* __restrict__ Abf, const int* __restrict__ flagp){
  int flag = *flagp;
  long i = (long)blockIdx.x*256 + threadIdx.x;
  unsigned char m = mask_elem(Am, i, flag);
  Abf[i] = f2bf(m ? A[i] : 0.f);
}

// Per-batch: transpose B_mask -> BmT[b,k,j], tar -> tarT[b,k,i]; compute
// kval[b,k] = any_i tar[b,i,k]; jtile-valid[b][jt] = any j in tile with
// (any_i Am[b,i,j]) & (any_k Bm[b,j,k]).
__global__ void prep_masks(const void* __restrict__ Am, const void* __restrict__ Bm,
                           const void* __restrict__ Tm,
                           unsigned char* __restrict__ BmT, unsigned char* __restrict__ tarT,
                           unsigned char* __restrict__ kval, unsigned char* __restrict__ jtv,
                           const int* __restrict__ flagp){
  int flag = *flagp;
  int b = blockIdx.x, t = threadIdx.x;       // t used as j (loops 1,2) and as k (loop 3)
  long base = (long)b * 65536;
  __shared__ unsigned char jv[256];

  unsigned char colA = 0;                     // any_i A_mask[b,i,t]
  for(int i=0;i<256;i++) colA |= mask_elem(Am, base + (long)i*256 + t, flag);

  unsigned char rB = 0;                       // any_k B_mask[b,t,k]; also transpose
  for(int kk=0;kk<256;kk++){
    unsigned char m = mask_elem(Bm, base + (long)t*256 + kk, flag);
    rB |= m;
    BmT[base + (long)kk*256 + t] = m;
  }

  unsigned char kv = 0;                       // any_i tar[b,i,t]; also transpose
  for(int i=0;i<256;i++){
    unsigned char m = mask_elem(Tm, base + (long)i*256 + t, flag);
    kv |= m;
    tarT[base + (long)t*256 + i] = m;
  }
  kval[b*256 + t] = kv;

  jv[t] = (unsigned char)(colA & rB);
  __syncthreads();
  if(t < 4){
    unsigned char v = 0;
    for(int x=0;x<64;x++) v |= jv[t*64 + x];
    jtv[b*4 + t] = v;
  }
}

__global__ __launch_bounds__(256) void mm_k(
    const unsigned short* __restrict__ Abf, const float* __restrict__ B,
    const unsigned char* __restrict__ BmT, const unsigned char* __restrict__ tarT,
    const unsigned char* __restrict__ kval, const unsigned int* __restrict__ jtw_,
    float* __restrict__ out)
{
  int bid = blockIdx.x;
  int b = bid >> 8, k = bid & 255;
  int t = threadIdx.x, lane = t & 63, wave = t >> 6;

  // B^T staged bf16: Bt[d=0..63][j=0..255], byte(d,j) = (d*512 + j*2) ^ ((d&7)<<4)
  __shared__ int4 Bt[2048];                  // 32 KiB

  f32x4 acc[4][4];
#pragma unroll
  for(int mi=0;mi<4;mi++)
#pragma unroll
    for(int ni=0;ni<4;ni++)
      acc[mi][ni] = (f32x4){0.f,0.f,0.f,0.f};

  int kv = kval[bid];
  unsigned jtw = jtw_[b];

  if(kv){
    // ---- stage masked bf16 B^T into LDS: thread owns d-column, one j-tile ----
    int d = t & 63, jt = t >> 6;
    if((jtw >> (jt*8)) & 0xff){
      const float* Bsrc = B + (size_t)b*4194304 + (size_t)k*64 + d;
      const unsigned char* bm = BmT + ((size_t)bid << 8);
#pragma unroll
      for(int jc=0; jc<8; jc++){
        int j0 = jt*64 + jc*8;
        int pk[4];
#pragma unroll
        for(int e=0; e<4; e++){
          int j = j0 + e*2;
          float f0 = bm[j]   ? Bsrc[(size_t)j*16384]     : 0.f;
          float f1 = bm[j+1] ? Bsrc[(size_t)(j+1)*16384] : 0.f;
          pk[e] = (int)f2bf(f0) | ((int)f2bf(f1) << 16);
        }
        int byt = (d*512 + j0*2) ^ ((d & 7) << 4);
        Bt[byt >> 4] = make_int4(pk[0], pk[1], pk[2], pk[3]);
      }
    }
  }
  __syncthreads();

  if(kv){
    // ---- compute: wave owns rows [wave*64, wave*64+64), all 64 d-columns ----
    const unsigned short* Arow = Abf + ((size_t)b << 16) + (size_t)(wave*64 + (lane & 15))*256;
    int qq = lane >> 4;
#pragma unroll
    for(int ks=0; ks<8; ks++){
      if(!((jtw >> ((ks>>1)*8)) & 0xff)) continue;
      int jcol = ks*32 + qq*8;
      short8 af[4], bfr[4];
#pragma unroll
      for(int mi=0; mi<4; mi++)
        af[mi] = *(const short8*)(Arow + mi*4096 + jcol);
#pragma unroll
      for(int ni=0; ni<4; ni++){
        int dd = ni*16 + (lane & 15);
        int byt = (dd*512 + jcol*2) ^ ((dd & 7) << 4);
        union { int4 i; short8 s; } u; u.i = Bt[byt >> 4];
        bfr[ni] = u.s;
      }
#pragma unroll
      for(int mi=0; mi<4; mi++)
#pragma unroll
        for(int ni=0; ni<4; ni++)
          acc[mi][ni] = __builtin_amdgcn_mfma_f32_16x16x32_bf16(af[mi], bfr[ni], acc[mi][ni], 0, 0, 0);
    }
  }

  // ---- epilogue: apply tar mask, write full tile (out is poisoned each call) ----
  const unsigned char* tb = tarT + ((size_t)bid << 8);
  float* ob = out + (size_t)b*4194304 + (size_t)k*64;
  int q = lane >> 4, c = lane & 15;
#pragma unroll
  for(int mi=0; mi<4; mi++){
#pragma unroll
    for(int r=0; r<4; r++){
      int i = wave*64 + mi*16 + q*4 + r;
      float tm = tb[i] ? 1.f : 0.f;
#pragma unroll
      for(int ni=0; ni<4; ni++)
        ob[(size_t)i*16384 + ni*16 + c] = acc[mi][ni][r] * tm;
    }
  }
}

extern "C" void kernel_launch(void* const* d_in, const int* in_sizes, int n_in,
                              void* d_out, int out_size, void* d_ws, size_t ws_size,
                              hipStream_t stream) {
  const float* A  = (const float*)d_in[0];
  const void*  Am = d_in[1];
  const float* Bd = (const float*)d_in[2];
  const void*  Bm = d_in[3];
  const void*  Tm = d_in[4];
  float* out = (float*)d_out;

  char* ws = (char*)d_ws;
  unsigned short* Abf  = (unsigned short*)ws;                 // 2 MiB
  unsigned char*  BmT  = (unsigned char*)(ws + (2u<<20));     // 1 MiB
  unsigned char*  tarT = (unsigned char*)(ws + (3u<<20));     // 1 MiB
  unsigned char*  kval = (unsigned char*)(ws + (4u<<20));     // 4 KiB
  unsigned char*  jtv  = (unsigned char*)(ws + (4u<<20) + 4096); // 64 B
  int*            flag = (int*)(ws + (4u<<20) + 8192);

  detect_k  <<<1, 1, 0, stream>>>((const unsigned char*)Am, flag);
  prep_A    <<<4096, 256, 0, stream>>>(A, Am, Abf, flag);
  prep_masks<<<16, 256, 0, stream>>>(Am, Bm, Tm, BmT, tarT, kval, jtv, flag);
  mm_k      <<<4096, 256, 0, stream>>>(Abf, Bd, BmT, tarT, kval,
                                       (const unsigned int*)jtv, out);
}

// Round 2
// 507.570 us; speedup vs baseline: 1.6723x; 1.6723x over previous
//
#include <hip/hip_runtime.h>

// out[b,i,k,d] = tar[b,i,k] * sum_j (A[b,i,j]*Am[b,i,j]) * (B[b,j,k,d]*Bm[b,j,k])
// B_SZ=16, N=256, D=64.  Per-(b,k) GEMM M=256,K=256,N=64 with bf16 MFMA 16x16x32.

typedef __attribute__((ext_vector_type(8))) short short8;
typedef __attribute__((ext_vector_type(4))) float f32x4;

static __device__ __forceinline__ unsigned short f2bf(float f){
  union { float f; unsigned u; } v; v.f = f;
  unsigned r = v.u + 0x7FFFu + ((v.u >> 16) & 1u);   // RNE
  return (unsigned short)(r >> 16);
}

// Mask storage dtype detected at runtime: 0=u8,1=i32,2=i64,3=f32,4=f64
static __device__ __forceinline__ unsigned char mask_elem(const void* p, long i, int flag){
  switch(flag){
    case 0:  return ((const unsigned char*)p)[i] ? 1 : 0;
    case 1:  return ((const int*)p)[i] ? 1 : 0;
    case 2:  return ((const long long*)p)[i] ? 1 : 0;
    case 3:  return ((const float*)p)[i] != 0.f ? 1 : 0;
    default: return ((const double*)p)[i] != 0.0 ? 1 : 0;
  }
}

__global__ void detect_k(const unsigned char* m, int* flag){
  unsigned char b0=m[0], b1=m[1], b3=m[3], b4=m[4];
  int f;
  if(b0==1 && b1==1)      f = 0;              // bool/u8: 1,1,...
  else if(b0==1)          f = (b4==1)?1:2;    // i32: 1,0,0,0,1 ; i64: 1,0,0,0,0
  else                    f = (b3==0x3f)?3:4; // f32 1.0f: 00 00 80 3f
  *flag = f;
}

// Pre-mask A -> bf16, 8 elems/thread, vectorized. grid 512 x 256.
__global__ __launch_bounds__(256) void prep_A2(const float* __restrict__ A,
    const void* __restrict__ Am, unsigned short* __restrict__ Abf,
    const int* __restrict__ flagp){
  int flag = *flagp;
  long base = ((long)blockIdx.x*256 + threadIdx.x)*8;
  float4 a0 = *(const float4*)(A+base), a1 = *(const float4*)(A+base+4);
  unsigned char m[8];
  if(flag == 0){
    unsigned long long w = *(const unsigned long long*)((const unsigned char*)Am + base);
#pragma unroll
    for(int e=0;e<8;e++) m[e] = (unsigned char)((w >> (e*8)) & 0xffull);
  } else if(flag == 1){
    const int4* p = (const int4*)((const int*)Am + base);
    int4 w0 = p[0], w1 = p[1];
    m[0]=w0.x!=0;m[1]=w0.y!=0;m[2]=w0.z!=0;m[3]=w0.w!=0;
    m[4]=w1.x!=0;m[5]=w1.y!=0;m[6]=w1.z!=0;m[7]=w1.w!=0;
  } else {
#pragma unroll
    for(int e=0;e<8;e++) m[e] = mask_elem(Am, base+e, flag);
  }
  float f[8] = {a0.x,a0.y,a0.z,a0.w,a1.x,a1.y,a1.z,a1.w};
  short8 o;
#pragma unroll
  for(int e=0;e<8;e++) o[e] = (short)f2bf(m[e] ? f[e] : 0.f);
  *(short8*)(Abf+base) = o;
}

// Tiled transpose + any-reductions for Bm and Tm. grid (16,16,2) x 256.
// which=0: BmT[b,k,j]=Bm[b,j,k], rowBbits[b][jt] bit j = any_k Bm[b,j,k]
// which=1: tarT[b,k,i]=Tm[b,i,k], kvalbits[b][kt] bit k = any_i Tm[b,i,k]
__global__ __launch_bounds__(256) void prep_masks2(const void* __restrict__ Bm,
    const void* __restrict__ Tm, unsigned char* __restrict__ BmT,
    unsigned char* __restrict__ tarT, unsigned long long* __restrict__ rowBbits,
    unsigned long long* __restrict__ kvalbits, const int* __restrict__ flagp){
  int flag = *flagp;
  int b = blockIdx.x;
  int tr = blockIdx.y >> 2, tc = blockIdx.y & 3;
  int which = blockIdx.z;
  const void* src = which ? Tm : Bm;
  __shared__ unsigned char tile[64][65];
  long base = (long)b*65536;
  int t = threadIdx.x;
#pragma unroll
  for(int p=0;p<16;p++){
    int rr = p*4 + (t>>6), cc = t&63;
    tile[rr][cc] = mask_elem(src, base + (long)(tr*64+rr)*256 + tc*64+cc, flag);
  }
  __syncthreads();
  unsigned char* dst = which ? tarT : BmT;
#pragma unroll
  for(int p=0;p<16;p++){
    int oc = p*4 + (t>>6), wj = t&63;
    dst[base + (long)(tc*64+oc)*256 + tr*64 + wj] = tile[wj][oc];
  }
  if(t < 64){
    unsigned char o = 0;
    if(which == 0){
#pragma unroll
      for(int cbit=0;cbit<64;cbit++) o |= tile[t][cbit];   // row j: OR over k-slice
      unsigned long long bal = __ballot(o != 0);
      if(t == 0) atomicOr(&rowBbits[b*4 + tr], bal);
    } else {
#pragma unroll
      for(int r=0;r<64;r++) o |= tile[r][t];               // col k: OR over i-slice
      unsigned long long bal = __ballot(o != 0);
      if(t == 0) atomicOr(&kvalbits[b*4 + tc], bal);
    }
  }
}

__global__ __launch_bounds__(256) void mm_k(
    const unsigned short* __restrict__ Abf, const float* __restrict__ B,
    const unsigned char* __restrict__ BmT, const unsigned char* __restrict__ tarT,
    const unsigned long long* __restrict__ kvalbits,
    const unsigned long long* __restrict__ rowBbits,
    float* __restrict__ out)
{
  int bid0 = blockIdx.x;
  int bid = (bid0 & 7)*512 + (bid0 >> 3);        // XCD-chunked swizzle (4096%8==0)
  int b = bid >> 8, k = bid & 255;
  int t = threadIdx.x, lane = t & 63, wave = t >> 6;

  // B^T staged bf16: Bt[d=0..63][j=0..255], byte(d,j) = (d*512 + j*2) ^ ((d&7)<<4)
  __shared__ int4 Bt[2048];                      // 32 KiB

  f32x4 acc[4][4];
#pragma unroll
  for(int mi=0;mi<4;mi++)
#pragma unroll
    for(int ni=0;ni<4;ni++)
      acc[mi][ni] = (f32x4){0.f,0.f,0.f,0.f};

  int kv = (int)((kvalbits[b*4 + (k>>6)] >> (k & 63)) & 1ull);
  unsigned long long rb0=rowBbits[b*4], rb1=rowBbits[b*4+1],
                     rb2=rowBbits[b*4+2], rb3=rowBbits[b*4+3];

  if(kv){
    // stage masked bf16 B^T: wave = j-tile, lane = d; j wave-uniform -> load skips
    int d = lane, jt = wave;
    unsigned long long rbw = jt==0?rb0 : jt==1?rb1 : jt==2?rb2 : rb3;
    if(rbw){
      const float* Bsrc = B + (size_t)b*4194304 + (size_t)k*64 + d;
      const unsigned long long* bm8 =
          (const unsigned long long*)(BmT + ((size_t)bid<<8) + jt*64);
#pragma unroll
      for(int jc=0; jc<8; jc++){
        int j0 = jt*64 + jc*8;
        unsigned long long mw = bm8[jc];
        int pk[4];
#pragma unroll
        for(int e=0; e<4; e++){
          int j = j0 + e*2;
          float f0 = 0.f, f1 = 0.f;
          if((mw >> (e*16)) & 0xffull)     f0 = Bsrc[(size_t)j << 14];
          if((mw >> (e*16+8)) & 0xffull)   f1 = Bsrc[(size_t)(j+1) << 14];
          pk[e] = (int)f2bf(f0) | ((int)f2bf(f1) << 16);
        }
        int byt = (d*512 + j0*2) ^ ((d & 7) << 4);
        Bt[byt >> 4] = make_int4(pk[0], pk[1], pk[2], pk[3]);
      }
    }
  }
  __syncthreads();

  if(kv){
    const unsigned short* Arow = Abf + ((size_t)b << 16) + (size_t)(wave*64 + (lane & 15))*256;
    int qq = lane >> 4;
#pragma unroll
    for(int ks=0; ks<8; ks++){
      unsigned long long rbw = (ks>>1)==0?rb0 : (ks>>1)==1?rb1 : (ks>>1)==2?rb2 : rb3;
      if(!rbw) continue;
      int jcol = ks*32 + qq*8;
      short8 af[4], bfr[4];
#pragma unroll
      for(int mi=0; mi<4; mi++)
        af[mi] = *(const short8*)(Arow + mi*4096 + jcol);
#pragma unroll
      for(int ni=0; ni<4; ni++){
        int dd = ni*16 + (lane & 15);
        int byt = (dd*512 + jcol*2) ^ ((dd & 7) << 4);
        union { int4 i; short8 s; } u; u.i = Bt[byt >> 4];
        bfr[ni] = u.s;
      }
      // swapped operands: D[d][i] -> lane holds 4 consecutive d at fixed i
#pragma unroll
      for(int mi=0; mi<4; mi++)
#pragma unroll
        for(int ni=0; ni<4; ni++)
          acc[mi][ni] = __builtin_amdgcn_mfma_f32_16x16x32_bf16(bfr[ni], af[mi], acc[mi][ni], 0, 0, 0);
    }
  }

  // epilogue: float4 stores; lane holds d = ni*16+q*4+r at i = wave*64+mi*16+c
  const unsigned char* tb = tarT + ((size_t)bid << 8);
  float* ob = out + (size_t)b*4194304 + (size_t)k*64;
  int q = lane >> 4, c = lane & 15;
#pragma unroll
  for(int mi=0; mi<4; mi++){
    int i = wave*64 + mi*16 + c;
    float tm = tb[i] ? 1.f : 0.f;
#pragma unroll
    for(int ni=0; ni<4; ni++){
      f32x4 v = acc[mi][ni];
      float4 w = make_float4(v[0]*tm, v[1]*tm, v[2]*tm, v[3]*tm);
      *(float4*)(ob + (size_t)i*16384 + ni*16 + q*4) = w;
    }
  }
}

extern "C" void kernel_launch(void* const* d_in, const int* in_sizes, int n_in,
                              void* d_out, int out_size, void* d_ws, size_t ws_size,
                              hipStream_t stream) {
  const float* A  = (const float*)d_in[0];
  const void*  Am = d_in[1];
  const float* Bd = (const float*)d_in[2];
  const void*  Bm = d_in[3];
  const void*  Tm = d_in[4];
  float* out = (float*)d_out;

  char* ws = (char*)d_ws;
  unsigned short* Abf  = (unsigned short*)ws;                          // 2 MiB
  unsigned char*  BmT  = (unsigned char*)(ws + (2u<<20));              // 1 MiB
  unsigned char*  tarT = (unsigned char*)(ws + (3u<<20));              // 1 MiB
  unsigned long long* rowBbits = (unsigned long long*)(ws + (4u<<20));         // 512 B
  unsigned long long* kvalbits = (unsigned long long*)(ws + (4u<<20) + 512);   // 512 B
  int*            flag = (int*)(ws + (4u<<20) + 1024);

  hipMemsetAsync(ws + (4u<<20), 0, 1024, stream);
  detect_k   <<<1, 1, 0, stream>>>((const unsigned char*)Am, flag);
  prep_A2    <<<512, 256, 0, stream>>>(A, Am, Abf, flag);
  prep_masks2<<<dim3(16,16,2), 256, 0, stream>>>(Bm, Tm, BmT, tarT, rowBbits, kvalbits, flag);
  mm_k       <<<4096, 256, 0, stream>>>(Abf, Bd, BmT, tarT, kvalbits, rowBbits, out);
}

// Round 3
// 488.933 us; speedup vs baseline: 1.7360x; 1.0381x over previous
//
#include <hip/hip_runtime.h>

// out[b,i,k,d] = tar[b,i,k] * sum_j (A[b,i,j]*Am[b,i,j]) * (B[b,j,k,d]*Bm[b,j,k])
// B_SZ=16, N=256, D=64.  Per-(b,k) GEMM M=256(i), N=64(d), K=256(j), bf16 MFMA.
// mm_k: BM=256 (4 waves x 64 i), BN=64 (one k), BK=64, double-buffered LDS for B^T,
// A fragments direct from global (L2-resident), branchless wave-uniform staging.

typedef __attribute__((ext_vector_type(8))) short short8;
typedef __attribute__((ext_vector_type(4))) float f32x4;

static __device__ __forceinline__ unsigned short f2bf(float f){
  union { float f; unsigned u; } v; v.f = f;
  unsigned r = v.u + 0x7FFFu + ((v.u >> 16) & 1u);   // RNE
  return (unsigned short)(r >> 16);
}

// Mask storage dtype detected at runtime: 0=u8,1=i32,2=i64,3=f32,4=f64
static __device__ __forceinline__ unsigned char mask_elem(const void* p, long i, int flag){
  switch(flag){
    case 0:  return ((const unsigned char*)p)[i] ? 1 : 0;
    case 1:  return ((const int*)p)[i] ? 1 : 0;
    case 2:  return ((const long long*)p)[i] ? 1 : 0;
    case 3:  return ((const float*)p)[i] != 0.f ? 1 : 0;
    default: return ((const double*)p)[i] != 0.0 ? 1 : 0;
  }
}

__global__ void detect_k(const unsigned char* m, int* flag){
  unsigned char b0=m[0], b1=m[1], b3=m[3], b4=m[4];
  int f;
  if(b0==1 && b1==1)      f = 0;
  else if(b0==1)          f = (b4==1)?1:2;
  else                    f = (b3==0x3f)?3:4;
  *flag = f;
}

// Pre-mask A -> bf16, 8 elems/thread. grid 512 x 256.
__global__ __launch_bounds__(256) void prep_A2(const float* __restrict__ A,
    const void* __restrict__ Am, unsigned short* __restrict__ Abf,
    const int* __restrict__ flagp){
  int flag = *flagp;
  long base = ((long)blockIdx.x*256 + threadIdx.x)*8;
  float4 a0 = *(const float4*)(A+base), a1 = *(const float4*)(A+base+4);
  unsigned char m[8];
  if(flag == 0){
    unsigned long long w = *(const unsigned long long*)((const unsigned char*)Am + base);
#pragma unroll
    for(int e=0;e<8;e++) m[e] = (unsigned char)((w >> (e*8)) & 0xffull);
  } else if(flag == 1){
    const int4* p = (const int4*)((const int*)Am + base);
    int4 w0 = p[0], w1 = p[1];
    m[0]=w0.x!=0;m[1]=w0.y!=0;m[2]=w0.z!=0;m[3]=w0.w!=0;
    m[4]=w1.x!=0;m[5]=w1.y!=0;m[6]=w1.z!=0;m[7]=w1.w!=0;
  } else {
#pragma unroll
    for(int e=0;e<8;e++) m[e] = mask_elem(Am, base+e, flag);
  }
  float f[8] = {a0.x,a0.y,a0.z,a0.w,a1.x,a1.y,a1.z,a1.w};
  short8 o;
#pragma unroll
  for(int e=0;e<8;e++) o[e] = (short)f2bf(m[e] ? f[e] : 0.f);
  *(short8*)(Abf+base) = o;
}

// Tiled transpose + any-reductions. grid (16,16,2) x 256.
__global__ __launch_bounds__(256) void prep_masks2(const void* __restrict__ Bm,
    const void* __restrict__ Tm, unsigned char* __restrict__ BmT,
    unsigned char* __restrict__ tarT, unsigned long long* __restrict__ rowBbits,
    unsigned long long* __restrict__ kvalbits, const int* __restrict__ flagp){
  int flag = *flagp;
  int b = blockIdx.x;
  int tr = blockIdx.y >> 2, tc = blockIdx.y & 3;
  int which = blockIdx.z;
  const void* src = which ? Tm : Bm;
  __shared__ unsigned char tile[64][65];
  long base = (long)b*65536;
  int t = threadIdx.x;
#pragma unroll
  for(int p=0;p<16;p++){
    int rr = p*4 + (t>>6), cc = t&63;
    tile[rr][cc] = mask_elem(src, base + (long)(tr*64+rr)*256 + tc*64+cc, flag);
  }
  __syncthreads();
  unsigned char* dst = which ? tarT : BmT;
#pragma unroll
  for(int p=0;p<16;p++){
    int oc = p*4 + (t>>6), wj = t&63;
    dst[base + (long)(tc*64+oc)*256 + tr*64 + wj] = tile[wj][oc];
  }
  if(t < 64){
    unsigned char o = 0;
    if(which == 0){
#pragma unroll
      for(int cbit=0;cbit<64;cbit++) o |= tile[t][cbit];
      unsigned long long bal = __ballot(o != 0);
      if(t == 0) atomicOr(&rowBbits[b*4 + tr], bal);
    } else {
#pragma unroll
      for(int r=0;r<64;r++) o |= tile[r][t];
      unsigned long long bal = __ballot(o != 0);
      if(t == 0) atomicOr(&kvalbits[b*4 + tc], bal);
    }
  }
}

__global__ __launch_bounds__(256, 3) void mm_k(
    const unsigned short* __restrict__ Abf, const float* __restrict__ B,
    const unsigned char* __restrict__ BmT, const unsigned char* __restrict__ tarT,
    const unsigned long long* __restrict__ kvalbits,
    const unsigned long long* __restrict__ rowBbits,
    float* __restrict__ out)
{
  int bid0 = blockIdx.x;
  int bid = (bid0 & 7)*512 + (bid0 >> 3);        // XCD-chunked swizzle (4096%8==0)
  int b = bid >> 8, k = bid & 255;
  int t = threadIdx.x, lane = t & 63, wave = t >> 6;

  // Per buffer: B^T tile, 64 d x 64 j bf16. byte(d,j') = (d*128 + j'*2) ^ ((d&7)<<4)
  __shared__ int4 Bt[2][512];                    // 2 x 8 KiB

  f32x4 acc[4][4];
#pragma unroll
  for(int mi=0;mi<4;mi++)
#pragma unroll
    for(int ni=0;ni<4;ni++)
      acc[mi][ni] = (f32x4){0.f,0.f,0.f,0.f};

  int kv = (int)((kvalbits[b*4 + (k>>6)] >> (k & 63)) & 1ull);
  int rb[4];
#pragma unroll
  for(int s=0;s<4;s++) rb[s] = kv && (rowBbits[b*4 + s] != 0ull);

  const float* Bsrc = B + (size_t)b*4194304 + (size_t)k*64 + lane;   // d = lane
  const unsigned char* bmrow = BmT + ((size_t)bid << 8);             // mask[j]

  // stage step s (j in [s*64, s*64+64)) into Bt[buf]; thread = (d=lane, jgrp=wave)
  auto STAGE = [&](int s, int buf){
    int j0 = s*64 + wave*16;
    uint4 mw = *(const uint4*)(bmrow + j0);       // 16 mask bytes, wave-uniform
    int byt0 = (lane*128 + wave*32) ^ ((lane & 7) << 4);
    if((mw.x | mw.y | mw.z | mw.w) != 0u){
      const float* p = Bsrc + (size_t)j0*16384;
      float f[16];
#pragma unroll
      for(int jj=0;jj<16;jj++) f[jj] = p[(size_t)jj*16384];   // branchless burst
      unsigned mb[4] = {mw.x, mw.y, mw.z, mw.w};
      int pk[8];
#pragma unroll
      for(int e=0;e<8;e++){
        unsigned w = mb[e>>1];
        unsigned m0 = (w >> ((e&1)*16))     & 0xffu;
        unsigned m1 = (w >> ((e&1)*16 + 8)) & 0xffu;
        float f0 = m0 ? f[2*e]   : 0.f;
        float f1 = m1 ? f[2*e+1] : 0.f;
        pk[e] = (int)f2bf(f0) | ((int)f2bf(f1) << 16);
      }
      Bt[buf][byt0 >> 4]        = make_int4(pk[0],pk[1],pk[2],pk[3]);
      Bt[buf][(byt0 ^ 16) >> 4] = make_int4(pk[4],pk[5],pk[6],pk[7]);
    } else {
      int4 z = make_int4(0,0,0,0);
      Bt[buf][byt0 >> 4]        = z;             // must zero: stale LDS otherwise
      Bt[buf][(byt0 ^ 16) >> 4] = z;
    }
  };

  auto COMPUTE = [&](int s, int buf){
    const unsigned short* Arow = Abf + ((size_t)b << 16)
        + (size_t)(wave*64 + (lane & 15))*256 + s*64;
    int qq = lane >> 4, c15 = lane & 15;
#pragma unroll
    for(int ksub=0; ksub<2; ksub++){
      int jc = ksub*32 + qq*8;                   // local j in [0,64)
      short8 af[4], bfr[4];
#pragma unroll
      for(int mi=0; mi<4; mi++)
        af[mi] = *(const short8*)(Arow + mi*4096 + jc);
#pragma unroll
      for(int ni=0; ni<4; ni++){
        int dd = ni*16 + c15;
        int byt = (dd*128 + jc*2) ^ ((dd & 7) << 4);
        union { int4 i; short8 s; } u; u.i = Bt[buf][byt >> 4];
        bfr[ni] = u.s;
      }
#pragma unroll
      for(int mi=0; mi<4; mi++)
#pragma unroll
        for(int ni=0; ni<4; ni++)
          acc[mi][ni] = __builtin_amdgcn_mfma_f32_16x16x32_bf16(bfr[ni], af[mi], acc[mi][ni], 0, 0, 0);
    }
  };

  if(rb[0]) STAGE(0, 0);
  __syncthreads();
#pragma unroll
  for(int s=0; s<4; s++){
    if(s < 3 && rb[s+1]) STAGE(s+1, (s+1)&1);    // prefetch next while computing
    if(rb[s])            COMPUTE(s, s&1);
    __syncthreads();
  }

  // epilogue: swapped-operand layout -> lane holds 4 consecutive d at fixed i
  const unsigned char* tb = tarT + ((size_t)bid << 8);
  float* ob = out + (size_t)b*4194304 + (size_t)k*64;
  int q = lane >> 4, c = lane & 15;
#pragma unroll
  for(int mi=0; mi<4; mi++){
    int i = wave*64 + mi*16 + c;
    float tm = tb[i] ? 1.f : 0.f;
#pragma unroll
    for(int ni=0; ni<4; ni++){
      f32x4 v = acc[mi][ni];
      float4 w = make_float4(v[0]*tm, v[1]*tm, v[2]*tm, v[3]*tm);
      *(float4*)(ob + (size_t)i*16384 + ni*16 + q*4) = w;
    }
  }
}

extern "C" void kernel_launch(void* const* d_in, const int* in_sizes, int n_in,
                              void* d_out, int out_size, void* d_ws, size_t ws_size,
                              hipStream_t stream) {
  const float* A  = (const float*)d_in[0];
  const void*  Am = d_in[1];
  const float* Bd = (const float*)d_in[2];
  const void*  Bm = d_in[3];
  const void*  Tm = d_in[4];
  float* out = (float*)d_out;

  char* ws = (char*)d_ws;
  unsigned short* Abf  = (unsigned short*)ws;                          // 2 MiB
  unsigned char*  BmT  = (unsigned char*)(ws + (2u<<20));              // 1 MiB
  unsigned char*  tarT = (unsigned char*)(ws + (3u<<20));              // 1 MiB
  unsigned long long* rowBbits = (unsigned long long*)(ws + (4u<<20));         // 512 B
  unsigned long long* kvalbits = (unsigned long long*)(ws + (4u<<20) + 512);   // 512 B
  int*            flag = (int*)(ws + (4u<<20) + 1024);

  hipMemsetAsync(ws + (4u<<20), 0, 1024, stream);
  detect_k   <<<1, 1, 0, stream>>>((const unsigned char*)Am, flag);
  prep_A2    <<<512, 256, 0, stream>>>(A, Am, Abf, flag);
  prep_masks2<<<dim3(16,16,2), 256, 0, stream>>>(Bm, Tm, BmT, tarT, rowBbits, kvalbits, flag);
  mm_k       <<<4096, 256, 0, stream>>>(Abf, Bd, BmT, tarT, kvalbits, rowBbits, out);
}